// Round 3
// baseline (85.601 us; speedup 1.0000x reference)
//
#include <hip/hip_runtime.h>
#include <hip/hip_bf16.h>

// Resonance synth:
//   out(b,e,n) = sum_f env_f(n) * sin(2*pi*freq_f*(n+1))
//   freq_f = (MIN + SCALE*f0_be) * (f+1), zeroed if >= 1.0 (contributes 0)
//   env_f(n) = linear frame->sample interp of res_bef^(t+1), t=0..127
//
// Round 3:
//  - phase via u32 fixed-point CHAIN over harmonics: ph_f = Q1*(f+1)*nn,
//    iterated as 4 parallel add-chains of stride 4*Q1*nn (no per-f mul_lo,
//    no Q[32] array). Aliased harmonics get env=0, so their phase is moot.
//  - interior blocks: env recurrence E[f] *= R[f] (w is per-thread constant
//    and frame advances exactly 1 per k-step). Edge blocks (y=0 clamp-low,
//    y=last clamp-high) use the general 3-op interp form.
//  - register state = E[32]+R[32] only (~82 VGPR, no spills), grid 2048
//    blocks = 8 waves/SIMD requested.

#define NSAMP 32768
#define NFRM  128
#define NF    32
#define NPAIR 64
#define CHUNKS 32
#define CHUNK (NSAMP / CHUNKS)   // 1024 samples per block
#define KIT   (CHUNK / 256)      // 4 samples per thread

// Runtime-dtype input load: bf16 or f32, selected by wave-uniform flag.
__device__ __forceinline__ float ldin(const void* p, int i, bool isbf) {
    if (isbf) {
        unsigned int w = ((unsigned int)((const unsigned short*)p)[i]) << 16;
        float f;
        __builtin_memcpy(&f, &w, 4);
        return f;
    }
    return ((const float*)p)[i];
}

extern "C" __global__ __launch_bounds__(256, 4)
void reson_kernel(const void* __restrict__ f0p,
                  const void* __restrict__ resp,
                  const void* __restrict__ facp,
                  void* __restrict__ outp)
{
    // dtype sniff: factors[0]==1.0f. f32 first word = 0x3F800000;
    // bf16 packs (1.0,2.0) = 0x40003F80.
    const bool isbf = (((const unsigned int*)facp)[0] != 0x3F800000u);

    const int pair = blockIdx.x;             // 0..63
    const int y    = blockIdx.y;             // 0..31
    const int tid  = threadIdx.x;            // 0..255
    const int n0   = y * CHUNK + tid;

    const float MINF = (float)(40.0 / 11025.0);
    const float FSC  = (float)(3960.0 / 11025.0);

    const float f0v = ldin(f0p, pair, isbf);
    const float sf0 = MINF + FSC * f0v;      // < 0.363, safe for u32 scale
    const unsigned int Q1 =
        (unsigned int)((double)sf0 * 4294967296.0 + 0.5);

    // frame coord at k=0 (align_corners=False): (n+0.5)/256 - 0.5, clipped
    const float c0raw = (n0 + 0.5f) * (1.0f / 256.0f) - 0.5f;
    float c0 = fminf(fmaxf(c0raw, 0.0f), (float)(NFRM - 1));
    const int   i0c = (int)c0;
    const float w0  = c0 - (float)i0c;
    const float c1  = c0raw + 1.0f;          // >= 0.5 always
    const float w1  = c1 - floorf(c1);       // weight for k >= 1
    const bool  clampLow = (c0raw < 0.0f);   // block y==0, tid<128 only
    const bool  edge = (y == 0) || (y == CHUNKS - 1);

    // Per-harmonic register state. Interior: E = current env value.
    // Edge: E = frame-endpoint M = r^(i0c+1).
    float E[NF], R[NF];
    #pragma unroll
    for (int f = 0; f < NF; ++f) {
        const float r = ldin(resp, pair * NF + f, isbf);
        R[f] = r;
        const float fac = ldin(facp, f, isbf);
        const float fr  = sf0 * fac;
        float A0 = exp2f(log2f(r) * (float)(i0c + 1));
        if (fr >= 1.0f) A0 = 0.0f;           // aliased harmonic: contributes 0
        // interior: pre-apply interp weight: env0 = A0*(1 + w0*(r-1))
        const float d = fmaf(A0, r, -A0);    // A0*r - A0
        E[f] = edge ? A0 : fmaf(w0, d, A0);
    }

    const int obase = pair * NSAMP + n0;

    if (!edge) {
        // ---- interior fast path: env is a pure *=R recurrence ----
        #pragma unroll
        for (int k = 0; k < KIT; ++k) {
            const unsigned int nn = (unsigned int)(n0 + 256 * k + 1);
            const unsigned int qn = Q1 * nn;     // one quarter-rate mul/sample
            unsigned int p[4] = { qn, qn + qn, qn + qn + qn, qn << 2 };
            const unsigned int q4 = qn << 2;
            float acc = 0.0f;
            #pragma unroll
            for (int f = 0; f < NF; ++f) {
                const int j = f & 3;
                const float t = (float)p[j] * 0x1p-32f;  // turns in [0,1)
                acc = fmaf(E[f], __builtin_amdgcn_sinf(t), acc);
                E[f] *= R[f];
                p[j] += q4;
            }
            const int o = obase + 256 * k;
            if (isbf) ((__hip_bfloat16*)outp)[o] = __float2bfloat16(acc);
            else      ((float*)outp)[o] = acc;
        }
    } else {
        // ---- edge path: general interp (handles low/high frame clamps) ----
        #pragma unroll
        for (int k = 0; k < KIT; ++k) {
            const unsigned int nn = (unsigned int)(n0 + 256 * k + 1);
            const unsigned int qn = Q1 * nn;
            unsigned int p[4] = { qn, qn + qn, qn + qn + qn, qn << 2 };
            const unsigned int q4 = qn << 2;
            const float wk = (k == 0)
                ? w0
                : ((c0raw + (float)k > (float)(NFRM - 1)) ? 0.0f : w1);
            const bool hold = (k == 0) && clampLow;  // stay on frame 0
            float acc = 0.0f;
            #pragma unroll
            for (int f = 0; f < NF; ++f) {
                const int j = f & 3;
                const float M   = E[f];
                const float An  = M * R[f];
                const float env = fmaf(wk, An - M, M);
                const float t = (float)p[j] * 0x1p-32f;
                acc = fmaf(env, __builtin_amdgcn_sinf(t), acc);
                E[f] = hold ? M : An;
                p[j] += q4;
            }
            const int o = obase + 256 * k;
            if (isbf) ((__hip_bfloat16*)outp)[o] = __float2bfloat16(acc);
            else      ((float*)outp)[o] = acc;
        }
    }
}

extern "C" void kernel_launch(void* const* d_in, const int* in_sizes, int n_in,
                              void* d_out, int out_size, void* d_ws, size_t ws_size,
                              hipStream_t stream) {
    (void)in_sizes; (void)n_in; (void)out_size; (void)d_ws; (void)ws_size;
    dim3 grid(NPAIR, CHUNKS);   // 64 x 32 = 2048 blocks, 8192 waves
    dim3 block(256);
    reson_kernel<<<grid, block, 0, stream>>>(d_in[0], d_in[1], d_in[2], d_out);
}